// Round 2
// baseline (566.671 us; speedup 1.0000x reference)
//
#include <hip/hip_runtime.h>
#include <stdint.h>

// Bahdanau additive attention, MI355X (gfx950).
// B=32, T=2048, H=1024, U=1024. All inputs fp32; output context [B,H] fp32.
//
// R5 changes vs R4:
//  - score_gemm ported to 256x256-tile, BK=64, 8-wave, 4-phase/K-tile schedule
//    (T3+T4+T5): raw s_barrier (no vmcnt drain), ONE counted s_waitcnt
//    vmcnt(2) per K-tile, s_setprio(1) around each 16-MFMA cluster.
//    Packed [k8][row][8] LDS layout kept (conflict-free ds_read_b128, linear
//    global_load_lds dest). B-frags register-cached per K-tile.
//  - score written as 4 slabs (score4); softmax sums k<4.

#define B_ 32
#define T_ 2048
#define H_ 1024
#define U_ 1024
#define M_ (B_ * T_)

typedef __bf16 bf16x8 __attribute__((ext_vector_type(8)));
typedef float f32x4 __attribute__((ext_vector_type(4)));

__device__ __forceinline__ unsigned f2b(float f) {  // fp32 -> bf16 bits, RNE
  unsigned u = __float_as_uint(f);
  return (u + 0x7FFFu + ((u >> 16) & 1u)) >> 16;
}
__device__ __forceinline__ float b2f(unsigned short u) {
  return __uint_as_float(((unsigned)u) << 16);
}
__device__ __forceinline__ float fast_tanh(float x) {
  float xc = fminf(fmaxf(x, -12.f), 12.f);
  float t = exp2f(xc * 2.885390081777927f);  // 2*log2(e)
  return (t - 1.f) * __builtin_amdgcn_rcpf(t + 1.f);
}

#define AS1 __attribute__((address_space(1)))
#define AS3 __attribute__((address_space(3)))
__device__ __forceinline__ void gld_lds16(const void* g, void* l) {
  __builtin_amdgcn_global_load_lds((AS1 const void*)g, (AS3 void*)l, 16, 0, 0);
}

// Raw barrier: does NOT drain vmcnt (unlike __syncthreads, which forces
// s_waitcnt vmcnt(0) and kills the staging pipeline). sched_barrier pins
// compiler motion across it.
__device__ __forceinline__ void BAR() {
  __builtin_amdgcn_sched_barrier(0);
  __builtin_amdgcn_s_barrier();
  __builtin_amdgcn_sched_barrier(0);
}

// ------------------------------------------------------------- conv_enc
// enc fp32 [M][1024] -> encA bf16 packed [mt][k8][ml][8] via LDS transpose.
__global__ __launch_bounds__(256) void conv_enc_k(const float4* __restrict__ in,
                                                  uint4* __restrict__ outA) {
  __shared__ uint4 L4[128 * 17];
  const int tx = threadIdx.x;
  const int band = blockIdx.x;      // 0..4095
  const int mt = band >> 3;
  const int R = (band & 7) << 4;    // ml base within 128-row tile
  const float4* src = in + (size_t)band * 4096;  // 16 rows * 256 float4
#pragma unroll
  for (int i = 0; i < 8; ++i) {
    int p = i * 256 + tx;           // pair index: row r, k8 chunk pc
    int r = p >> 7, pc = p & 127;
    float4 a = src[r * 256 + pc * 2];
    float4 b = src[r * 256 + pc * 2 + 1];
    uint4 o;
    o.x = f2b(a.x) | (f2b(a.y) << 16);
    o.y = f2b(a.z) | (f2b(a.w) << 16);
    o.z = f2b(b.x) | (f2b(b.y) << 16);
    o.w = f2b(b.z) | (f2b(b.w) << 16);
    L4[pc * 17 + r] = o;
  }
  __syncthreads();
  const int r2 = tx & 15, kq = (tx >> 4) & 3, w = tx >> 6;
#pragma unroll
  for (int j = 0; j < 8; ++j) {
    int k8 = j * 16 + w * 4 + kq;
    outA[((size_t)mt * 128 + k8) * 128 + R + r2] = L4[k8 * 17 + r2];
  }
}

// Ua [H][U] fp32 -> Ub [(H/8)][U][8] bf16, dense 16B writes.
__global__ __launch_bounds__(256) void conv_ua_k(const float* __restrict__ in,
                                                 uint4* __restrict__ out) {
  int id = blockIdx.x * 256 + threadIdx.x;  // 131072 = 128 h8 * 1024 u
  int h8 = id >> 10, u = id & 1023;
  const float* p = in + (size_t)(h8 << 3) * U_ + u;
  uint4 o;
  o.x = f2b(p[0]) | (f2b(p[U_]) << 16);
  o.y = f2b(p[2 * U_]) | (f2b(p[3 * U_]) << 16);
  o.z = f2b(p[4 * U_]) | (f2b(p[5 * U_]) << 16);
  o.w = f2b(p[6 * U_]) | (f2b(p[7 * U_]) << 16);
  out[(size_t)h8 * U_ + u] = o;
}

// ------------------------------------------------------------- dec_proj
__global__ __launch_bounds__(256) void decproj_k(const float* __restrict__ dh,
                                                 const float* __restrict__ Wa,
                                                 float* __restrict__ dp4) {
  const int u = blockIdx.x * 256 + threadIdx.x;
  const int b = blockIdx.y, hz = blockIdx.z;
  const float* d = dh + b * H_ + hz * 256;
  const float* w = Wa + (size_t)(hz * 256) * U_ + u;
  float a0 = 0.f, a1 = 0.f, a2 = 0.f, a3 = 0.f;
#pragma unroll 4
  for (int h = 0; h < 256; h += 4) {
    a0 = fmaf(d[h + 0], w[(size_t)(h + 0) * U_], a0);
    a1 = fmaf(d[h + 1], w[(size_t)(h + 1) * U_], a1);
    a2 = fmaf(d[h + 2], w[(size_t)(h + 2) * U_], a2);
    a3 = fmaf(d[h + 3], w[(size_t)(h + 3) * U_], a3);
  }
  dp4[((hz * B_ + b) * U_) + u] = (a0 + a1) + (a2 + a3);
}

// ------------------------------------------------------------- fused GEMM
// 256x256 tile, BK=64, 8 waves (2M x 4N), LDS 128 KiB double-buffered.
// Schedule per K-tile (4 phases):
//   ph0: STAGE(kt+1,A0) ; vmcnt(2) ; BAR ; ds_read B(8)+A(4) ; prio1 16xMFMA prio0 ; BAR
//   ph1-3: STAGE(kt+1,h) ; ds_read A(4) ; prio1 16xMFMA prio0 ; BAR
// vmcnt ledger: 8 loads/thread per K-tile (2/phase); at ph0 of tile kt the
// in-flight set = 8 (tile kt) + 2 (just-issued kt+1 A0) -> vmcnt(2) waits
// exactly tile kt. Last tile uses vmcnt(0). Loads stay in flight across
// barriers (raw s_barrier, no drain).
__global__ __launch_bounds__(512, 2) void score_gemm_k(
    const unsigned short* __restrict__ encA,  // packed [mt][k8][ml][8]
    const unsigned short* __restrict__ Ub,    // [k8][N][8]
    const float* __restrict__ dp4,            // [4][B][U]
    const float* __restrict__ Va,             // [U]
    float* __restrict__ score4)               // [4][M]
{
  __shared__ union {
    struct {
      alignas(16) unsigned short As[2][8][256][8];  // 64 KiB (2 bufs)
      alignas(16) unsigned short Bs[2][8][256][8];  // 64 KiB
    } t;
    float sred[256][4];  // epilogue scratch (4 KiB)
  } sm;

  // XCD swizzle: bx = s*32 + nt2*8 + x -> mt2 = s*8+x, nt2. The 4 nt2-blocks
  // of one mt2 are 8 apart -> same XCD consecutively; 512 KiB A-panel stays
  // in that XCD's L2.
  const int bx = blockIdx.x;
  const int x = bx & 7, gsl = (bx >> 3) & 3, s = bx >> 5;
  const int mt2 = s * 8 + x, nt2 = gsl;
  const int n0 = nt2 << 8;
  const int tid = threadIdx.x;
  const int wv = tid >> 6, ln = tid & 63;
  const int wm = wv >> 2, wn = wv & 3;  // 2 x 4 wave grid
  const int quad = ln >> 4, l16 = ln & 15;

  const unsigned short* encT = encA + (size_t)mt2 * (2 * 128 * 128 * 8);

  // Stage half hf (0,1 = A row-halves; 2,3 = B col-halves) of K-tile kt into
  // buffer bsel. 2 gld_lds16 per thread; each wave covers two 1 KiB chunks.
  auto STAGE = [&](int kt, int hf, int bsel) {
#pragma unroll
    for (int r = 0; r < 2; ++r) {
      int c = r * 8 + wv;                 // chunk 0..15
      int k8 = c >> 1, rg = (c & 1) << 6; // k8 slot, 64-row group
      if (hf < 2) {
        const unsigned short* ga =
            encT + (((size_t)(hf * 128 + kt * 8 + k8) * 128) + rg + ln) * 8;
        gld_lds16(ga, &sm.t.As[bsel][k8][hf * 128 + rg][0]);
      } else {
        int h2 = hf - 2;
        const unsigned short* gb =
            Ub + (((size_t)(kt * 8 + k8) * U_) + n0 + h2 * 128 + rg + ln) * 8;
        gld_lds16(gb, &sm.t.Bs[bsel][k8][h2 * 128 + rg][0]);
      }
    }
  };

  f32x4 acc[8][4];
  const f32x4 zero = {0.f, 0.f, 0.f, 0.f};
#pragma unroll
  for (int i = 0; i < 8; ++i)
#pragma unroll
    for (int j = 0; j < 4; ++j) acc[i][j] = zero;

  // Prologue: stage all 4 halves of tile 0 into buf 0 (8 loads/thread).
#pragma unroll
  for (int hf = 0; hf < 4; ++hf) STAGE(0, hf, 0);

  bf16x8 bfr[4][2];  // B frags, register-cached per K-tile

#pragma unroll 2
  for (int kt = 0; kt < 16; ++kt) {
    const int cb = kt & 1, nb = cb ^ 1;

    // ---- phase 0
    if (kt < 15) {
      STAGE(kt + 1, 0, nb);
      asm volatile("s_waitcnt vmcnt(2)" ::: "memory");
    } else {
      asm volatile("s_waitcnt vmcnt(0)" ::: "memory");
    }
    BAR();  // all waves' tile-kt stages complete -> LDS resident
#pragma unroll
    for (int nt = 0; nt < 4; ++nt)
#pragma unroll
      for (int kk = 0; kk < 2; ++kk)
        bfr[nt][kk] = *(const bf16x8*)&sm.t
                           .Bs[cb][kk * 4 + quad][wn * 64 + nt * 16 + l16][0];
    {
      bf16x8 af[2][2];
#pragma unroll
      for (int i = 0; i < 2; ++i)
#pragma unroll
        for (int kk = 0; kk < 2; ++kk)
          af[i][kk] = *(const bf16x8*)&sm.t
                           .As[cb][kk * 4 + quad][wm * 128 + i * 16 + l16][0];
      __builtin_amdgcn_s_setprio(1);
#pragma unroll
      for (int kk = 0; kk < 2; ++kk)
#pragma unroll
        for (int i = 0; i < 2; ++i)
#pragma unroll
          for (int nt = 0; nt < 4; ++nt)
            acc[i][nt] = __builtin_amdgcn_mfma_f32_16x16x32_bf16(
                af[i][kk], bfr[nt][kk], acc[i][nt], 0, 0, 0);
      __builtin_amdgcn_s_setprio(0);
    }
    BAR();

    // ---- phases 1..3
#pragma unroll
    for (int p = 1; p < 4; ++p) {
      if (kt < 15) STAGE(kt + 1, p, nb);
      bf16x8 af[2][2];
#pragma unroll
      for (int i = 0; i < 2; ++i)
#pragma unroll
        for (int kk = 0; kk < 2; ++kk)
          af[i][kk] =
              *(const bf16x8*)&sm.t.As[cb][kk * 4 + quad]
                                      [wm * 128 + (p * 2 + i) * 16 + l16][0];
      __builtin_amdgcn_s_setprio(1);
#pragma unroll
      for (int kk = 0; kk < 2; ++kk)
#pragma unroll
        for (int i = 0; i < 2; ++i)
#pragma unroll
          for (int nt = 0; nt < 4; ++nt)
            acc[p * 2 + i][nt] = __builtin_amdgcn_mfma_f32_16x16x32_bf16(
                af[i][kk], bfr[nt][kk], acc[p * 2 + i][nt], 0, 0, 0);
      __builtin_amdgcn_s_setprio(0);
      BAR();
    }
  }

  // ------------------------------------------------------ epilogue
  // v = sum_fn tanh(acc + dp) * Va per row; shfl-reduce over l16 (16-lane
  // groups), 4 KiB sred for the cross-wn reduce.
  const int bq = mt2 >> 3;  // batch (256-row tile never straddles b)
  float va[4], dpv[4];
#pragma unroll
  for (int fn = 0; fn < 4; ++fn) {
    int col = n0 + wn * 64 + fn * 16 + l16;
    va[fn] = Va[col];
    dpv[fn] = dp4[bq * U_ + col] + dp4[B_ * U_ + bq * U_ + col] +
              dp4[2 * B_ * U_ + bq * U_ + col] +
              dp4[3 * B_ * U_ + bq * U_ + col];
  }
  asm volatile("s_waitcnt vmcnt(0) lgkmcnt(0)" ::: "memory");
  BAR();  // tile-buffer reads done everywhere; safe to reuse as sred
#pragma unroll
  for (int fm = 0; fm < 8; ++fm) {
#pragma unroll
    for (int rr = 0; rr < 4; ++rr) {
      float v = 0.f;
#pragma unroll
      for (int fn = 0; fn < 4; ++fn)
        v += fast_tanh(acc[fm][fn][rr] + dpv[fn]) * va[fn];
#pragma unroll
      for (int off = 1; off < 16; off <<= 1) v += __shfl_xor(v, off);
      if (l16 == 0) sm.sred[wm * 128 + fm * 16 + quad * 4 + rr][wn] = v;
    }
  }
  BAR();
  if (tid < 256) {
    float ssum = sm.sred[tid][0] + sm.sred[tid][1] + sm.sred[tid][2] +
                 sm.sred[tid][3];
    score4[(size_t)nt2 * M_ + mt2 * 256 + tid] = ssum;
  }
}

// ------------------------------------------------------------- softmax
// Sums the 4 ntile slabs, then softmax over T per b; writes alpha.
__global__ __launch_bounds__(256) void softmax_k(const float* __restrict__ score4,
                                                 float* __restrict__ alpha) {
  const int b = blockIdx.x, tid = threadIdx.x;
  __shared__ float red[4];
  float4 v0 = {0.f, 0.f, 0.f, 0.f}, v1 = {0.f, 0.f, 0.f, 0.f};
#pragma unroll
  for (int k = 0; k < 4; ++k) {
    const float4* p = (const float4*)(score4 + (size_t)k * M_ + b * T_);
    float4 x0 = p[tid * 2], x1 = p[tid * 2 + 1];
    v0.x += x0.x; v0.y += x0.y; v0.z += x0.z; v0.w += x0.w;
    v1.x += x1.x; v1.y += x1.y; v1.z += x1.z; v1.w += x1.w;
  }
  float m = fmaxf(fmaxf(fmaxf(v0.x, v0.y), fmaxf(v0.z, v0.w)),
                  fmaxf(fmaxf(v1.x, v1.y), fmaxf(v1.z, v1.w)));
#pragma unroll
  for (int off = 32; off >= 1; off >>= 1) m = fmaxf(m, __shfl_xor(m, off));
  if ((tid & 63) == 0) red[tid >> 6] = m;
  __syncthreads();
  m = fmaxf(fmaxf(red[0], red[1]), fmaxf(red[2], red[3]));
  __syncthreads();
  const float l2e = 1.4426950408889634f;
  float e[8];
  e[0] = exp2f((v0.x - m) * l2e); e[1] = exp2f((v0.y - m) * l2e);
  e[2] = exp2f((v0.z - m) * l2e); e[3] = exp2f((v0.w - m) * l2e);
  e[4] = exp2f((v1.x - m) * l2e); e[5] = exp2f((v1.y - m) * l2e);
  e[6] = exp2f((v1.z - m) * l2e); e[7] = exp2f((v1.w - m) * l2e);
  float sum = (e[0] + e[1]) + (e[2] + e[3]) + (e[4] + e[5]) + (e[6] + e[7]);
#pragma unroll
  for (int off = 32; off >= 1; off >>= 1) sum += __shfl_xor(sum, off);
  if ((tid & 63) == 0) red[tid >> 6] = sum;
  __syncthreads();
  float inv = 1.f / (red[0] + red[1] + red[2] + red[3]);
  float4* a4 = (float4*)(alpha + b * T_);
  float4 o0, o1;
  o0.x = e[0] * inv; o0.y = e[1] * inv; o0.z = e[2] * inv; o0.w = e[3] * inv;
  o1.x = e[4] * inv; o1.y = e[5] * inv; o1.z = e[6] * inv; o1.w = e[7] * inv;
  a4[tid * 2] = o0;
  a4[tid * 2 + 1] = o1;
}

// ------------------------------------------------------------- context
__global__ __launch_bounds__(256) void context_k(const uint4* __restrict__ encA,
                                                 const float* __restrict__ alpha,
                                                 float* __restrict__ ctxp) {
  const int tx = threadIdx.x & 127, th = threadIdx.x >> 7;
  const int b = blockIdx.y, bt = blockIdx.x;
  const int mt = b * 16 + bt;
  const uint4* base = encA + ((size_t)mt * 128 + tx) * 128 + th * 64;
  const float* al = alpha + b * T_ + bt * 128 + th * 64;
  float a[8];
#pragma unroll
  for (int j = 0; j < 8; ++j) a[j] = 0.f;
#pragma unroll 4
  for (int i = 0; i < 64; ++i) {
    float w = al[i];
    uint4 e = base[i];
    a[0] = fmaf(w, b2f((unsigned short)e.x), a[0]);
    a[1] = fmaf(w, b2f((unsigned short)(e.x >> 16)), a[1]);
    a[2] = fmaf(w, b2f((unsigned short)e.y), a[2]);
    a[3] = fmaf(w, b2f((unsigned short)(e.y >> 16)), a[3]);
    a[4] = fmaf(w, b2f((unsigned short)e.z), a[4]);
    a[5] = fmaf(w, b2f((unsigned short)(e.z >> 16)), a[5]);
    a[6] = fmaf(w, b2f((unsigned short)e.w), a[6]);
    a[7] = fmaf(w, b2f((unsigned short)(e.w >> 16)), a[7]);
  }
  __shared__ float cred[2][128][8];
#pragma unroll
  for (int j = 0; j < 8; ++j) cred[th][tx][j] = a[j];
  __syncthreads();
  if (th == 0) {
    float* o = ctxp + (size_t)mt * H_ + tx * 8;
#pragma unroll
    for (int j = 0; j < 8; ++j) o[j] = cred[0][tx][j] + cred[1][tx][j];
  }
}

// Final reduce: out[b,h] = sum_bt ctxp[b*16+bt][h]
__global__ __launch_bounds__(256) void ctx_red_k(const float* __restrict__ ctxp,
                                                 float* __restrict__ out) {
  int id = blockIdx.x * 256 + threadIdx.x;  // 32768 = B*H
  int b = id >> 10, h = id & 1023;
  float s = 0.f;
#pragma unroll
  for (int bt = 0; bt < 16; ++bt) s += ctxp[((size_t)(b * 16 + bt)) * H_ + h];
  out[id] = s;
}

// ------------------------------------------------------------- launch
extern "C" void kernel_launch(void* const* d_in, const int* in_sizes, int n_in,
                              void* d_out, int out_size, void* d_ws, size_t ws_size,
                              hipStream_t stream) {
  const float* enc = (const float*)d_in[0];
  const float* dh  = (const float*)d_in[1];
  const float* Wa  = (const float*)d_in[2];
  const float* Ua  = (const float*)d_in[3];
  const float* Va  = (const float*)d_in[4];

  char* ws = (char*)d_ws;
  unsigned short* encA = (unsigned short*)ws;                     // 128 MiB
  unsigned short* Ub   = (unsigned short*)(ws + 134217728);       // 2 MiB
  float* dp4    = (float*)(ws + 136314880);                       // 512 KiB
  float* score4 = (float*)(ws + 136839168);                       // 1 MiB (of 2 MiB region)
  float* alpha  = dp4;     // overlay: dp4 dead after score_gemm
  float* ctxp   = score4;  // overlay: score4 dead after softmax (2 MiB region)

  conv_enc_k<<<4096, 256, 0, stream>>>((const float4*)enc, (uint4*)encA);
  conv_ua_k<<<512, 256, 0, stream>>>(Ua, (uint4*)Ub);
  decproj_k<<<dim3(4, 32, 4), 256, 0, stream>>>(dh, Wa, dp4);
  score_gemm_k<<<1024, 512, 0, stream>>>(encA, Ub, dp4, Va, score4);
  softmax_k<<<32, 256, 0, stream>>>(score4, alpha);
  context_k<<<dim3(16, 32), 256, 0, stream>>>((const uint4*)encA, alpha, ctxp);
  ctx_red_k<<<128, 256, 0, stream>>>(ctxp, (float*)d_out);
}

// Round 3
// 562.128 us; speedup vs baseline: 1.0081x; 1.0081x over previous
//
#include <hip/hip_runtime.h>
#include <stdint.h>

// Bahdanau additive attention, MI355X (gfx950).
// B=32, T=2048, H=1024, U=1024. All inputs fp32; output context [B,H] fp32.
//
// R6 changes vs R5:
//  - GEMM reverted to the proven R4 2-barrier 128^2 structure (R5's 4-phase
//    counted-vmcnt schedule was null: L2-fed staging makes the barrier drain
//    cheap, so the deep pipeline had nothing to hide).
//  - prep_k: conv_enc + conv_ua + decproj + d_out zeroing merged into ONE
//    grid-partitioned kernel (overlap on CUs, -2 launches).
//  - ctx_k: softmax recomputed per context block (score8 slabs L2-resident),
//    context partials atomicAdd'ed straight into d_out (zeroed by prep_k).
//    Eliminates softmax_k, ctx_red_k, alpha and ctxp round-trips.
//  - 7 launches -> 3.

#define B_ 32
#define T_ 2048
#define H_ 1024
#define U_ 1024
#define M_ (B_ * T_)

typedef __bf16 bf16x8 __attribute__((ext_vector_type(8)));
typedef float f32x4 __attribute__((ext_vector_type(4)));

__device__ __forceinline__ unsigned f2b(float f) {  // fp32 -> bf16 bits, RNE
  unsigned u = __float_as_uint(f);
  return (u + 0x7FFFu + ((u >> 16) & 1u)) >> 16;
}
__device__ __forceinline__ float b2f(unsigned short u) {
  return __uint_as_float(((unsigned)u) << 16);
}
__device__ __forceinline__ float fast_tanh(float x) {
  float xc = fminf(fmaxf(x, -12.f), 12.f);
  float t = exp2f(xc * 2.885390081777927f);  // 2*log2(e)
  return (t - 1.f) * __builtin_amdgcn_rcpf(t + 1.f);
}

#define AS1 __attribute__((address_space(1)))
#define AS3 __attribute__((address_space(3)))
__device__ __forceinline__ void gld_lds16(const void* g, void* l) {
  __builtin_amdgcn_global_load_lds((AS1 const void*)g, (AS3 void*)l, 16, 0, 0);
}

// ------------------------------------------------------------- prep
// Grid-partitioned fusion of four independent prologue tasks:
//   bx in [0,4096)     : conv_enc  (enc fp32 -> encA bf16 packed, LDS transpose)
//   bx in [4096,4608)  : conv_ua   (Ua fp32 -> Ub bf16 packed)
//   bx in [4608,5120)  : decproj   (dp4[hz][b][u] partials)
//   bx in [5120,5248)  : zero d_out (poisoned by harness; ctx_k atomicAdds)
__global__ __launch_bounds__(256) void prep_k(
    const float4* __restrict__ enc, uint4* __restrict__ outA,
    const float* __restrict__ Ua, uint4* __restrict__ Ub,
    const float* __restrict__ dh, const float* __restrict__ Wa,
    float* __restrict__ dp4, float* __restrict__ outz) {
  const int bx = blockIdx.x;
  const int tx = threadIdx.x;

  if (bx < 4096) {
    // ---- conv_enc: reads 16 rows (64 KB fp32), writes packed bf16.
    __shared__ uint4 L4[128 * 17];
    const int band = bx;
    const int mt = band >> 3;
    const int R = (band & 7) << 4;  // ml base within 128-row tile
    const float4* src = enc + (size_t)band * 4096;  // 16 rows * 256 float4
#pragma unroll
    for (int i = 0; i < 8; ++i) {
      int p = i * 256 + tx;  // pair index: row r, k8 chunk pc
      int r = p >> 7, pc = p & 127;
      float4 a = src[r * 256 + pc * 2];
      float4 b = src[r * 256 + pc * 2 + 1];
      uint4 o;
      o.x = f2b(a.x) | (f2b(a.y) << 16);
      o.y = f2b(a.z) | (f2b(a.w) << 16);
      o.z = f2b(b.x) | (f2b(b.y) << 16);
      o.w = f2b(b.z) | (f2b(b.w) << 16);
      L4[pc * 17 + r] = o;
    }
    __syncthreads();
    const int r2 = tx & 15, kq = (tx >> 4) & 3, w = tx >> 6;
#pragma unroll
    for (int j = 0; j < 8; ++j) {
      int k8 = j * 16 + w * 4 + kq;
      outA[((size_t)mt * 128 + k8) * 128 + R + r2] = L4[k8 * 17 + r2];
    }
  } else if (bx < 4608) {
    // ---- conv_ua: Ua [H][U] -> Ub [(H/8)][U][8] bf16, dense 16B writes.
    int id = (bx - 4096) * 256 + tx;  // 131072 = 128 h8 * 1024 u
    int h8 = id >> 10, u = id & 1023;
    const float* p = Ua + (size_t)(h8 << 3) * U_ + u;
    uint4 o;
    o.x = f2b(p[0]) | (f2b(p[U_]) << 16);
    o.y = f2b(p[2 * U_]) | (f2b(p[3 * U_]) << 16);
    o.z = f2b(p[4 * U_]) | (f2b(p[5 * U_]) << 16);
    o.w = f2b(p[6 * U_]) | (f2b(p[7 * U_]) << 16);
    Ub[(size_t)h8 * U_ + u] = o;
  } else if (bx < 5120) {
    // ---- decproj: dp4[hz][b][u] partial over 256-h chunk.
    int g = bx - 4608;  // 512 = 4 uc * 32 b * 4 hz
    const int u = (g & 3) * 256 + tx;
    const int b = (g >> 2) & 31, hz = g >> 7;
    const float* d = dh + b * H_ + hz * 256;
    const float* w = Wa + (size_t)(hz * 256) * U_ + u;
    float a0 = 0.f, a1 = 0.f, a2 = 0.f, a3 = 0.f;
#pragma unroll 4
    for (int h = 0; h < 256; h += 4) {
      a0 = fmaf(d[h + 0], w[(size_t)(h + 0) * U_], a0);
      a1 = fmaf(d[h + 1], w[(size_t)(h + 1) * U_], a1);
      a2 = fmaf(d[h + 2], w[(size_t)(h + 2) * U_], a2);
      a3 = fmaf(d[h + 3], w[(size_t)(h + 3) * U_], a3);
    }
    dp4[((hz * B_ + b) * U_) + u] = (a0 + a1) + (a2 + a3);
  } else {
    // ---- zero d_out (32768 floats).
    outz[(bx - 5120) * 256 + tx] = 0.f;
  }
}

// ------------------------------------------------------------- fused GEMM
// Proven R4 structure: 128^2 tile, 2-barrier K-loop, gld_lds-direct staging.
// XCD swizzle: bx = (s<<6)|(m3<<3)|x  ->  mtile = s*8+x, ntile = m3.
// Round-robin XCD dispatch => the 8 ntile-blocks of one mtile run
// consecutively on one XCD; A-tile (256 KiB) stays in that XCD's L2.
__global__ __launch_bounds__(256, 2) void score_gemm_k(
    const unsigned short* __restrict__ encA,  // packed [mt][k8][ml][8]
    const unsigned short* __restrict__ Ub,    // [k8][N][8]
    const float* __restrict__ dp4,            // [4][B][U]
    const float* __restrict__ Va,             // [U]
    float* __restrict__ score8)               // [8][M]
{
  __shared__ union {
    struct {
      alignas(16) unsigned short As[8][128][8];  // [k8][m][j] 16 KiB
      alignas(16) unsigned short Bs[8][128][8];  // [k8][n][j] 16 KiB
    } t;
    float sred[128 * 33];  // epilogue scratch, stride-33 pad
  } sm;

  const int bx = blockIdx.x;
  const int mtile = ((bx >> 6) << 3) | (bx & 7), ntile = (bx >> 3) & 7;
  const int m0 = mtile << 7, n0 = ntile << 7;
  const int tid = threadIdx.x;
  const int wv = tid >> 6, ln = tid & 63;
  const int wm = wv & 1, wn = wv >> 1;
  const int quad = ln >> 4, l16 = ln & 15;

  f32x4 acc[4][4];
  const f32x4 zero = {0.f, 0.f, 0.f, 0.f};
#pragma unroll
  for (int i = 0; i < 4; ++i)
#pragma unroll
    for (int j = 0; j < 4; ++j) acc[i][j] = zero;

  const unsigned short* encT = encA + (size_t)mtile * (128 * 128 * 8);

  for (int k0 = 0; k0 < H_; k0 += 64) {
    __syncthreads();
#pragma unroll
    for (int c = 0; c < 4; ++c) {
      int chunk = (wv << 2) + c;  // 0..15
      int k8 = chunk >> 1, half = chunk & 1;
      const unsigned short* ga =
          encT + (((size_t)((k0 >> 3) + k8) * 128) + (half << 6) + ln) * 8;
      gld_lds16(ga, &sm.t.As[k8][half << 6][0]);
      const unsigned short* gb =
          Ub + (((size_t)((k0 >> 3) + k8) * U_) + n0 + (half << 6) + ln) * 8;
      gld_lds16(gb, &sm.t.Bs[k8][half << 6][0]);
    }
    __syncthreads();

#pragma unroll
    for (int kk = 0; kk < 2; ++kk) {
      int k8b = (kk << 2) + quad;
      bf16x8 af[4], bf[4];
#pragma unroll
      for (int mt = 0; mt < 4; ++mt)
        af[mt] = *(const bf16x8*)&sm.t.As[k8b][(wm << 6) + (mt << 4) + l16][0];
#pragma unroll
      for (int nt = 0; nt < 4; ++nt)
        bf[nt] = *(const bf16x8*)&sm.t.Bs[k8b][(wn << 6) + (nt << 4) + l16][0];
#pragma unroll
      for (int mt = 0; mt < 4; ++mt)
#pragma unroll
        for (int nt = 0; nt < 4; ++nt)
          acc[mt][nt] = __builtin_amdgcn_mfma_f32_16x16x32_bf16(
              af[mt], bf[nt], acc[mt][nt], 0, 0, 0);
    }
  }

  // Epilogue: v = sum_nt tanh(acc + dp) * Va; LDS reduce over 32 col-groups.
  // C/D layout: col = l16, row = quad*4 + r.
  const int bq = m0 >> 11;  // batch (tile never straddles b)
  float va[4], dpv[4];
#pragma unroll
  for (int nt = 0; nt < 4; ++nt) {
    int col = n0 + (wn << 6) + (nt << 4) + l16;
    va[nt] = Va[col];
    dpv[nt] = dp4[bq * U_ + col] + dp4[B_ * U_ + bq * U_ + col] +
              dp4[2 * B_ * U_ + bq * U_ + col] + dp4[3 * B_ * U_ + bq * U_ + col];
  }
  __syncthreads();  // LDS tile reads done; reuse as sred
#pragma unroll
  for (int mt = 0; mt < 4; ++mt) {
#pragma unroll
    for (int r = 0; r < 4; ++r) {
      float v = 0.f;
#pragma unroll
      for (int nt = 0; nt < 4; ++nt)
        v += fast_tanh(acc[mt][nt][r] + dpv[nt]) * va[nt];
      int row = (wm << 6) + (mt << 4) + (quad << 2) + r;
      sm.sred[row * 33 + (wn << 4) + l16] = v;
    }
  }
  __syncthreads();
  if (tid < 128) {
    const float* p = &sm.sred[tid * 33];
    float s = 0.f;
#pragma unroll
    for (int j = 0; j < 32; ++j) s += p[j];
    score8[(size_t)ntile * M_ + m0 + tid] = s;
  }
}

// ------------------------------------------------------------- context
// Per (b, bt) block: recompute b's softmax from score8 (L2-resident, 32 KB
// reads), then accumulate this block's 128-t slice of context and atomicAdd
// into out[b][h] (zeroed by prep_k).
__global__ __launch_bounds__(256) void ctx_k(const uint4* __restrict__ encA,
                                             const float* __restrict__ score8,
                                             float* __restrict__ out) {
  const int b = blockIdx.y, bt = blockIdx.x, tid = threadIdx.x;
  __shared__ float s_sc[2048];   // summed scores for this b (8 KB)
  __shared__ float a_s[128];     // alpha slice for this bt
  __shared__ float red[4];
  __shared__ float cred[2][128][8];

  // 1) sum the 8 ntile slabs; keep in regs + LDS.
  float4 v0 = {0.f, 0.f, 0.f, 0.f}, v1 = {0.f, 0.f, 0.f, 0.f};
#pragma unroll
  for (int k = 0; k < 8; ++k) {
    const float4* p = (const float4*)(score8 + (size_t)k * M_ + b * T_);
    float4 x0 = p[tid * 2], x1 = p[tid * 2 + 1];
    v0.x += x0.x; v0.y += x0.y; v0.z += x0.z; v0.w += x0.w;
    v1.x += x1.x; v1.y += x1.y; v1.z += x1.z; v1.w += x1.w;
  }
  ((float4*)s_sc)[tid * 2] = v0;
  ((float4*)s_sc)[tid * 2 + 1] = v1;

  // 2) block max.
  float m = fmaxf(fmaxf(fmaxf(v0.x, v0.y), fmaxf(v0.z, v0.w)),
                  fmaxf(fmaxf(v1.x, v1.y), fmaxf(v1.z, v1.w)));
#pragma unroll
  for (int off = 32; off >= 1; off >>= 1) m = fmaxf(m, __shfl_xor(m, off));
  if ((tid & 63) == 0) red[tid >> 6] = m;
  __syncthreads();
  m = fmaxf(fmaxf(red[0], red[1]), fmaxf(red[2], red[3]));
  __syncthreads();

  // 3) block sum of exp.
  const float l2e = 1.4426950408889634f;
  float sum = exp2f((v0.x - m) * l2e) + exp2f((v0.y - m) * l2e) +
              exp2f((v0.z - m) * l2e) + exp2f((v0.w - m) * l2e) +
              exp2f((v1.x - m) * l2e) + exp2f((v1.y - m) * l2e) +
              exp2f((v1.z - m) * l2e) + exp2f((v1.w - m) * l2e);
#pragma unroll
  for (int off = 32; off >= 1; off >>= 1) sum += __shfl_xor(sum, off);
  if ((tid & 63) == 0) red[tid >> 6] = sum;
  __syncthreads();
  const float inv = 1.f / (red[0] + red[1] + red[2] + red[3]);

  // 4) alpha slice for this block's 128 t's.
  if (tid < 128) a_s[tid] = exp2f((s_sc[bt * 128 + tid] - m) * l2e) * inv;
  __syncthreads();

  // 5) context partial over this 128-t slice.
  const int tx = tid & 127, th = tid >> 7;
  const int mt = b * 16 + bt;
  const uint4* base = encA + ((size_t)mt * 128 + tx) * 128 + th * 64;
  float a[8];
#pragma unroll
  for (int j = 0; j < 8; ++j) a[j] = 0.f;
#pragma unroll 4
  for (int i = 0; i < 64; ++i) {
    float w = a_s[th * 64 + i];
    uint4 e = base[i];
    a[0] = fmaf(w, b2f((unsigned short)e.x), a[0]);
    a[1] = fmaf(w, b2f((unsigned short)(e.x >> 16)), a[1]);
    a[2] = fmaf(w, b2f((unsigned short)e.y), a[2]);
    a[3] = fmaf(w, b2f((unsigned short)(e.y >> 16)), a[3]);
    a[4] = fmaf(w, b2f((unsigned short)e.z), a[4]);
    a[5] = fmaf(w, b2f((unsigned short)(e.z >> 16)), a[5]);
    a[6] = fmaf(w, b2f((unsigned short)e.w), a[6]);
    a[7] = fmaf(w, b2f((unsigned short)(e.w >> 16)), a[7]);
  }
#pragma unroll
  for (int j = 0; j < 8; ++j) cred[th][tx][j] = a[j];
  __syncthreads();
  if (th == 0) {
    float* o = out + (size_t)b * H_ + tx * 8;
#pragma unroll
    for (int j = 0; j < 8; ++j)
      atomicAdd(&o[j], cred[0][tx][j] + cred[1][tx][j]);
  }
}

// ------------------------------------------------------------- launch
extern "C" void kernel_launch(void* const* d_in, const int* in_sizes, int n_in,
                              void* d_out, int out_size, void* d_ws, size_t ws_size,
                              hipStream_t stream) {
  const float* enc = (const float*)d_in[0];
  const float* dh  = (const float*)d_in[1];
  const float* Wa  = (const float*)d_in[2];
  const float* Ua  = (const float*)d_in[3];
  const float* Va  = (const float*)d_in[4];

  char* ws = (char*)d_ws;
  unsigned short* encA = (unsigned short*)ws;                     // 128 MiB
  unsigned short* Ub   = (unsigned short*)(ws + 134217728);       // 2 MiB
  float* dp4    = (float*)(ws + 136314880);                       // 512 KiB
  float* score8 = (float*)(ws + 136839168);                       // 2 MiB

  prep_k<<<5248, 256, 0, stream>>>((const float4*)enc, (uint4*)encA, Ua,
                                   (uint4*)Ub, dh, Wa, dp4, (float*)d_out);
  score_gemm_k<<<4096, 256, 0, stream>>>(encA, Ub, dp4, Va, score8);
  ctx_k<<<dim3(16, 32), 256, 0, stream>>>((const uint4*)encA, score8,
                                          (float*)d_out);
}